// Round 7
// baseline (194.159 us; speedup 1.0000x reference)
//
#include <hip/hip_runtime.h>

#define IMG 512
#define CS 52                     // shorts per Ht column: 48-slot ring + 4 pad (104 B)
#define CH_STRIDE (16 * CS)       // 832 shorts: one channel (16 cols) of one wave
#define WV_STRIDE (5 * CH_STRIDE) // 4160 shorts: one wave's 5 channels

typedef short short8  __attribute__((ext_vector_type(8)));
typedef float floatx4 __attribute__((ext_vector_type(4)));
typedef int   intx2   __attribute__((ext_vector_type(2)));

// 1D Gaussian (sigma=1.5, K=11) — identical values to rounds 1-6.
__device__ static constexpr float W11F[11] = {
    0.00102838f, 0.00759876f, 0.03600077f, 0.10936069f, 0.21300554f,
    0.26601173f,
    0.21300554f, 0.10936069f, 0.03600077f, 0.00759876f, 0.00102838f};

// pack two fp32 -> two bf16 (round-half-up; finite positive values)
__device__ __forceinline__ unsigned pack2bf16(float a, float b) {
    const unsigned ua = __float_as_uint(a) + 0x8000u;
    const unsigned ub = __float_as_uint(b) + 0x8000u;
    return __builtin_amdgcn_perm(ub, ua, 0x07060302u);
}

__device__ __forceinline__ void ht_store(ushort* p, floatx4 c) {
    intx2 d;
    d.x = (int)pack2bf16(c[0], c[1]);
    d.y = (int)pack2bf16(c[2], c[3]);
    *(intx2*)p = d;               // 8-B aligned: CS*2 and offsets are mult of 8
}

__device__ __forceinline__ short8 ht_load(const ushort* p) {
    union { intx2 d[2]; short8 s; } u;
    u.d[0] = *(const intx2*)p;
    u.d[1] = *(const intx2*)(p + 4);
    return u.s;
}

// Block = 4 waves. Wave = 16 out-cols x 128 out-rows, processed as 8 windows
// of 16 rows with a rolling 3-tile (48-row) Ht ring in LDS and a 2-deep
// global-load pipeline (load for tile t+2 is consumed one iteration later).
__global__ __launch_bounds__(256, 4) void ssim_mfma_ring(
        const float* __restrict__ pred, const float* __restrict__ gt,
        float* __restrict__ partials)
{
    __shared__ ushort Ht[4 * WV_STRIDE];   // 33,280 B
    __shared__ ushort wlut[16];
    __shared__ float wsum[4];

    const int tid  = threadIdx.x;
    const int wv   = tid >> 6;
    const int lane = tid & 63;
    const int n    = lane & 15;
    const int quad = lane >> 4;

    if (tid < 16) {
        const float w = (tid < 11) ? W11F[tid] : 0.f;
        wlut[tid] = (ushort)((__float_as_uint(w) + 0x8000u) >> 16);
    }
    __syncthreads();

    // band fragment: w[(quad*8+j) - n - 3]; B in H-pass, A in V-pass.
    short8 band;
#pragma unroll
    for (int j = 0; j < 8; ++j) {
        const int t = quad * 8 + j - n - 3;
        band[j] = (short)wlut[((unsigned)t < 11u) ? t : 15];
    }

    const int bx = blockIdx.x, by = blockIdx.y, plane = blockIdx.z;
    const long pb = (long)plane * (IMG * IMG);
    const int xs  = bx * 64 + wv * 16 - 8;  // 32-col input window start
    const int y0  = by * 128;               // 128-row output strip
    ushort* ht    = &Ht[wv * WV_STRIDE];
    const bool cols_ok = (xs >= 0) && (xs + 32 <= IMG);

// stage tile t (16 input rows starting at y0-8+16t) into registers
#define LOADT(t, pf, gf)                                                     \
    {                                                                        \
        const int ys  = y0 - 8 + (t) * 16;                                   \
        const int row = ys + n;                                              \
        const int c0  = xs + quad * 8;                                       \
        if (cols_ok && ys >= 0 && ys + 16 <= IMG) {                          \
            const float* pr = pred + pb + (long)row * IMG + c0;              \
            const float* gr = gt   + pb + (long)row * IMG + c0;              \
            *(float4*)&pf[0] = *(const float4*)pr;                           \
            *(float4*)&pf[4] = *(const float4*)(pr + 4);                     \
            *(float4*)&gf[0] = *(const float4*)gr;                           \
            *(float4*)&gf[4] = *(const float4*)(gr + 4);                     \
        } else {                                                             \
            const bool rv = (unsigned)row < (unsigned)IMG;                   \
            const int rowc = rv ? row : 0;                                   \
            const float* pr = pred + pb + (long)rowc * IMG;                  \
            const float* gr = gt   + pb + (long)rowc * IMG;                  \
            _Pragma("unroll")                                                \
            for (int j = 0; j < 8; ++j) {                                    \
                const int cc = c0 + j;                                       \
                const bool ok = rv && ((unsigned)cc < (unsigned)IMG);        \
                const int ccc = ok ? cc : 0;                                 \
                const float pv = pr[ccc], gv = gr[ccc];                      \
                pf[j] = ok ? pv : 0.f;                                       \
                gf[j] = ok ? gv : 0.f;                                       \
            }                                                                \
        }                                                                    \
    }

// H-conv tile t via 5 MFMAs, store into ring slot t%3 (k = slot*16 + m)
#define COMPT(t, pf, gf)                                                     \
    {                                                                        \
        union { unsigned u[4]; short8 s; } ap, ag, app, agg, apg;            \
        _Pragma("unroll")                                                    \
        for (int h = 0; h < 4; ++h) {                                        \
            const float p0 = pf[2*h], p1 = pf[2*h+1];                        \
            const float g0 = gf[2*h], g1 = gf[2*h+1];                        \
            ap.u [h] = pack2bf16(p0, p1);                                    \
            ag.u [h] = pack2bf16(g0, g1);                                    \
            app.u[h] = pack2bf16(p0 * p0, p1 * p1);                          \
            agg.u[h] = pack2bf16(g0 * g0, g1 * g1);                          \
            apg.u[h] = pack2bf16(p0 * g0, p1 * g1);                          \
        }                                                                    \
        const floatx4 z = {0.f, 0.f, 0.f, 0.f};                              \
        const floatx4 cp  = __builtin_amdgcn_mfma_f32_16x16x32_bf16(ap.s,  band, z, 0, 0, 0); \
        const floatx4 cg  = __builtin_amdgcn_mfma_f32_16x16x32_bf16(ag.s,  band, z, 0, 0, 0); \
        const floatx4 cpp = __builtin_amdgcn_mfma_f32_16x16x32_bf16(app.s, band, z, 0, 0, 0); \
        const floatx4 cgg = __builtin_amdgcn_mfma_f32_16x16x32_bf16(agg.s, band, z, 0, 0, 0); \
        const floatx4 cpg = __builtin_amdgcn_mfma_f32_16x16x32_bf16(apg.s, band, z, 0, 0, 0); \
        const int wb = n * CS + ((t) % 3) * 16 + quad * 4;                   \
        ht_store(&ht[0 * CH_STRIDE + wb], cp);                               \
        ht_store(&ht[1 * CH_STRIDE + wb], cg);                               \
        ht_store(&ht[2 * CH_STRIDE + wb], cpp);                              \
        ht_store(&ht[3 * CH_STRIDE + wb], cgg);                              \
        ht_store(&ht[4 * CH_STRIDE + wb], cpg);                              \
    }

    const float C1 = 1e-4f, C2 = 9e-4f;
    float lsum = 0.f;

    float pbuf[2][8], gbuf[2][8];
    // prologue: tiles 0,1 in flight; tile 0 composed
    LOADT(0, pbuf[0], gbuf[0])
    LOADT(1, pbuf[1], gbuf[1])
    COMPT(0, pbuf[0], gbuf[0])

#pragma unroll
    for (int w = 0; w < 8; ++w) {
        // issue next tile's loads first (consumed next iteration)
        if (w < 7)
            LOADT(w + 2, pbuf[w & 1], gbuf[w & 1])
        // compose tile w+1 (loaded last iteration) -> ring slot (w+1)%3
        COMPT(w + 1, pbuf[(w + 1) & 1], gbuf[(w + 1) & 1])

        // V window w: k-rows = ring tiles w%3 (k 0..15) and (w+1)%3 (k 16..31)
        const int s_lo = w % 3, s_hi = (w + 1) % 3;
        const int koff = ((quad < 2) ? s_lo : s_hi) * 16 + (quad & 1) * 8;
        const int rb   = n * CS + koff;
        const short8 bp  = ht_load(&ht[0 * CH_STRIDE + rb]);
        const short8 bg  = ht_load(&ht[1 * CH_STRIDE + rb]);
        const short8 bpp = ht_load(&ht[2 * CH_STRIDE + rb]);
        const short8 bgg = ht_load(&ht[3 * CH_STRIDE + rb]);
        const short8 bpg = ht_load(&ht[4 * CH_STRIDE + rb]);

        const floatx4 z = {0.f, 0.f, 0.f, 0.f};
        const floatx4 mp  = __builtin_amdgcn_mfma_f32_16x16x32_bf16(band, bp,  z, 0, 0, 0);
        const floatx4 mg  = __builtin_amdgcn_mfma_f32_16x16x32_bf16(band, bg,  z, 0, 0, 0);
        const floatx4 mpp = __builtin_amdgcn_mfma_f32_16x16x32_bf16(band, bpp, z, 0, 0, 0);
        const floatx4 mgg = __builtin_amdgcn_mfma_f32_16x16x32_bf16(band, bgg, z, 0, 0, 0);
        const floatx4 mpg = __builtin_amdgcn_mfma_f32_16x16x32_bf16(band, bpg, z, 0, 0, 0);

#pragma unroll
        for (int r = 0; r < 4; ++r) {
            const float mu1 = mp[r], mu2 = mg[r];
            const float mu1sq = mu1 * mu1, mu2sq = mu2 * mu2, mu12 = mu1 * mu2;
            const float s1  = mpp[r] - mu1sq;
            const float s2  = mgg[r] - mu2sq;
            const float s12 = mpg[r] - mu12;
            const float num = (2.f * mu12 + C1) * (2.f * s12 + C2);
            const float den = (mu1sq + mu2sq + C1) * (s1 + s2 + C2);
            lsum += num * __builtin_amdgcn_rcpf(den);
        }
    }

    // ---- block reduction -> one partial per block ----
#pragma unroll
    for (int off = 32; off > 0; off >>= 1)
        lsum += __shfl_down(lsum, off);
    if (lane == 0) wsum[wv] = lsum;
    __syncthreads();
    if (tid == 0)
        partials[(plane * 4 + by) * 8 + bx] =
            wsum[0] + wsum[1] + wsum[2] + wsum[3];
}

__global__ __launch_bounds__(1024) void ssim_finalize(
        const float* __restrict__ partials, float* __restrict__ out,
        int nparts, double inv_n)
{
    __shared__ double ws[16];
    double s = 0.0;
    for (int i = threadIdx.x; i < nparts; i += 1024)
        s += (double)partials[i];
#pragma unroll
    for (int off = 32; off > 0; off >>= 1)
        s += __shfl_down(s, off);
    if ((threadIdx.x & 63) == 0) ws[threadIdx.x >> 6] = s;
    __syncthreads();
    if (threadIdx.x == 0) {
        double t = 0.0;
#pragma unroll
        for (int i = 0; i < 16; ++i) t += ws[i];
        out[0] = (float)(1.0 - t * inv_n);
    }
}

extern "C" void kernel_launch(void* const* d_in, const int* in_sizes, int n_in,
                              void* d_out, int out_size, void* d_ws, size_t ws_size,
                              hipStream_t stream)
{
    const float* pred = (const float*)d_in[0];
    const float* gt   = (const float*)d_in[1];
    float* out        = (float*)d_out;
    float* partials   = (float*)d_ws;          // 8*4*48 = 1536 floats

    const long n = (long)in_sizes[0];
    const int planes = (int)(n / (long)(IMG * IMG));   // B*C = 48

    dim3 grid(8, 4, planes);                   // 64-col x 128-row strips
    ssim_mfma_ring<<<grid, 256, 0, stream>>>(pred, gt, partials);
    ssim_finalize<<<1, 1024, 0, stream>>>(partials, out,
                                          8 * 4 * planes, 1.0 / (double)n);
}

// Round 8
// 161.160 us; speedup vs baseline: 1.2048x; 1.2048x over previous
//
#include <hip/hip_runtime.h>

#define IMG 512
#define CS 36                     // shorts per Ht column: 2 ring slots (32) + 4 pad
#define CH_STRIDE (16 * CS)       // 576 shorts: one channel (16 cols) of one wave
#define WV_STRIDE (5 * CH_STRIDE) // 2880 shorts: one wave's 5 channels

typedef short short8  __attribute__((ext_vector_type(8)));
typedef float floatx4 __attribute__((ext_vector_type(4)));
typedef int   intx2   __attribute__((ext_vector_type(2)));

// 1D Gaussian (sigma=1.5, K=11) — identical values to rounds 1-7.
__device__ static constexpr float W11F[11] = {
    0.00102838f, 0.00759876f, 0.03600077f, 0.10936069f, 0.21300554f,
    0.26601173f,
    0.21300554f, 0.10936069f, 0.03600077f, 0.00759876f, 0.00102838f};

// pack two fp32 -> two bf16 (round-half-up; finite positive values)
__device__ __forceinline__ unsigned pack2bf16(float a, float b) {
    const unsigned ua = __float_as_uint(a) + 0x8000u;
    const unsigned ub = __float_as_uint(b) + 0x8000u;
    return __builtin_amdgcn_perm(ub, ua, 0x07060302u);
}

__device__ __forceinline__ void ht_store(ushort* p, floatx4 c) {
    intx2 d;
    d.x = (int)pack2bf16(c[0], c[1]);
    d.y = (int)pack2bf16(c[2], c[3]);
    *(intx2*)p = d;               // 8-B aligned by construction
}

__device__ __forceinline__ short8 ht_load(const ushort* p) {
    union { intx2 d[2]; short8 s; } u;
    u.d[0] = *(const intx2*)p;
    u.d[1] = *(const intx2*)(p + 4);
    return u.s;
}

// Block = 4 waves. Wave = 16 out-cols x 64 out-rows: 5 staged 16-row tiles
// feed 4 output windows through a 2-slot LDS ring (tile t -> slot t&1).
// Straight-line schedule, named register buffers only (no spillable arrays).
__global__ __launch_bounds__(256, 4) void ssim_mfma_ring2(
        const float* __restrict__ pred, const float* __restrict__ gt,
        float* __restrict__ partials)
{
    __shared__ ushort Ht[4 * WV_STRIDE];   // 23,040 B
    __shared__ ushort wlut[16];
    __shared__ float wsum[4];

    const int tid  = threadIdx.x;
    const int wv   = tid >> 6;
    const int lane = tid & 63;
    const int n    = lane & 15;
    const int quad = lane >> 4;

    if (tid < 16) {
        const float w = (tid < 11) ? W11F[tid] : 0.f;
        wlut[tid] = (ushort)((__float_as_uint(w) + 0x8000u) >> 16);
    }
    __syncthreads();

    // band fragment: w[(quad*8+j) - n - 3]; B in H-pass, A in V-pass.
    short8 band;
#pragma unroll
    for (int j = 0; j < 8; ++j) {
        const int t = quad * 8 + j - n - 3;
        band[j] = (short)wlut[((unsigned)t < 11u) ? t : 15];
    }

    const int bx = blockIdx.x, by = blockIdx.y, plane = blockIdx.z;
    const long pb = (long)plane * (IMG * IMG);
    const float* pplane = pred + pb;
    const float* gplane = gt + pb;
    const int xs  = bx * 64 + wv * 16 - 8;  // 32-col input window start
    const int y0  = by * 64;                // 64-row output strip
    ushort* ht    = &Ht[wv * WV_STRIDE];
    const bool cols_ok = (xs >= 0) && (xs + 32 <= IMG);

// stage tile t (16 input rows starting at y0-8+16t) into named buffers
#define LOADT(t, pf, gf)                                                     \
    {                                                                        \
        const int ys  = y0 - 8 + (t) * 16;                                   \
        const int row = ys + n;                                              \
        const int c0  = xs + quad * 8;                                       \
        if (cols_ok && ys >= 0 && ys + 16 <= IMG) {                          \
            const float* pr = pplane + (long)row * IMG + c0;                 \
            const float* gr = gplane + (long)row * IMG + c0;                 \
            *(float4*)&pf[0] = *(const float4*)pr;                           \
            *(float4*)&pf[4] = *(const float4*)(pr + 4);                     \
            *(float4*)&gf[0] = *(const float4*)gr;                           \
            *(float4*)&gf[4] = *(const float4*)(gr + 4);                     \
        } else {                                                             \
            const bool rv = (unsigned)row < (unsigned)IMG;                   \
            const int rowc = rv ? row : 0;                                   \
            const float* pr = pplane + (long)rowc * IMG;                     \
            const float* gr = gplane + (long)rowc * IMG;                     \
            _Pragma("unroll")                                                \
            for (int j = 0; j < 8; ++j) {                                    \
                const int cc = c0 + j;                                       \
                const bool ok = rv && ((unsigned)cc < (unsigned)IMG);        \
                const int ccc = ok ? cc : 0;                                 \
                const float pv = pr[ccc], gv = gr[ccc];                      \
                pf[j] = ok ? pv : 0.f;                                       \
                gf[j] = ok ? gv : 0.f;                                       \
            }                                                                \
        }                                                                    \
    }

// H-conv tile t via 5 MFMAs, store into ring slot t&1 (k = slot*16 + m)
#define COMPT(t, pf, gf)                                                     \
    {                                                                        \
        union { unsigned u[4]; short8 s; } ap, ag, app, agg, apg;            \
        _Pragma("unroll")                                                    \
        for (int h = 0; h < 4; ++h) {                                        \
            const float p0 = pf[2*h], p1 = pf[2*h+1];                        \
            const float g0 = gf[2*h], g1 = gf[2*h+1];                        \
            ap.u [h] = pack2bf16(p0, p1);                                    \
            ag.u [h] = pack2bf16(g0, g1);                                    \
            app.u[h] = pack2bf16(p0 * p0, p1 * p1);                          \
            agg.u[h] = pack2bf16(g0 * g0, g1 * g1);                          \
            apg.u[h] = pack2bf16(p0 * g0, p1 * g1);                          \
        }                                                                    \
        const floatx4 z = {0.f, 0.f, 0.f, 0.f};                              \
        const floatx4 cp  = __builtin_amdgcn_mfma_f32_16x16x32_bf16(ap.s,  band, z, 0, 0, 0); \
        const floatx4 cg  = __builtin_amdgcn_mfma_f32_16x16x32_bf16(ag.s,  band, z, 0, 0, 0); \
        const floatx4 cpp = __builtin_amdgcn_mfma_f32_16x16x32_bf16(app.s, band, z, 0, 0, 0); \
        const floatx4 cgg = __builtin_amdgcn_mfma_f32_16x16x32_bf16(agg.s, band, z, 0, 0, 0); \
        const floatx4 cpg = __builtin_amdgcn_mfma_f32_16x16x32_bf16(apg.s, band, z, 0, 0, 0); \
        const int wb = n * CS + ((t) & 1) * 16 + quad * 4;                   \
        ht_store(&ht[0 * CH_STRIDE + wb], cp);                               \
        ht_store(&ht[1 * CH_STRIDE + wb], cg);                               \
        ht_store(&ht[2 * CH_STRIDE + wb], cpp);                              \
        ht_store(&ht[3 * CH_STRIDE + wb], cgg);                              \
        ht_store(&ht[4 * CH_STRIDE + wb], cpg);                              \
    }

// V window w: lower 16 k-rows from ring slot SLO, upper from slot SHI
#define VPASS(SLO, SHI)                                                      \
    {                                                                        \
        const int koff = ((quad < 2) ? (SLO) : (SHI)) * 16 + (quad & 1) * 8; \
        const int rb   = n * CS + koff;                                      \
        const short8 bp  = ht_load(&ht[0 * CH_STRIDE + rb]);                 \
        const short8 bg  = ht_load(&ht[1 * CH_STRIDE + rb]);                 \
        const short8 bpp = ht_load(&ht[2 * CH_STRIDE + rb]);                 \
        const short8 bgg = ht_load(&ht[3 * CH_STRIDE + rb]);                 \
        const short8 bpg = ht_load(&ht[4 * CH_STRIDE + rb]);                 \
        const floatx4 z = {0.f, 0.f, 0.f, 0.f};                              \
        const floatx4 mp  = __builtin_amdgcn_mfma_f32_16x16x32_bf16(band, bp,  z, 0, 0, 0); \
        const floatx4 mg  = __builtin_amdgcn_mfma_f32_16x16x32_bf16(band, bg,  z, 0, 0, 0); \
        const floatx4 mpp = __builtin_amdgcn_mfma_f32_16x16x32_bf16(band, bpp, z, 0, 0, 0); \
        const floatx4 mgg = __builtin_amdgcn_mfma_f32_16x16x32_bf16(band, bgg, z, 0, 0, 0); \
        const floatx4 mpg = __builtin_amdgcn_mfma_f32_16x16x32_bf16(band, bpg, z, 0, 0, 0); \
        _Pragma("unroll")                                                    \
        for (int r = 0; r < 4; ++r) {                                        \
            const float mu1 = mp[r], mu2 = mg[r];                            \
            const float mu1sq = mu1 * mu1, mu2sq = mu2 * mu2;                \
            const float mu12 = mu1 * mu2;                                    \
            const float s1  = mpp[r] - mu1sq;                                \
            const float s2  = mgg[r] - mu2sq;                                \
            const float s12 = mpg[r] - mu12;                                 \
            const float num = (2.f * mu12 + C1) * (2.f * s12 + C2);          \
            const float den = (mu1sq + mu2sq + C1) * (s1 + s2 + C2);         \
            lsum += num * __builtin_amdgcn_rcpf(den);                        \
        }                                                                    \
    }

    const float C1 = 1e-4f, C2 = 9e-4f;
    float lsum = 0.f;

    // named buffers, constant indices only -> stays in VGPRs
    float pE[8], gE[8], pO[8], gO[8];

    LOADT(0, pE, gE)
    LOADT(1, pO, gO)
    COMPT(0, pE, gE)          // slot 0
    LOADT(2, pE, gE)
    COMPT(1, pO, gO)          // slot 1
    VPASS(0, 1)               // window 0: tiles 0,1
    LOADT(3, pO, gO)
    COMPT(2, pE, gE)          // slot 0
    VPASS(1, 0)               // window 1: tiles 1,2
    LOADT(4, pE, gE)
    COMPT(3, pO, gO)          // slot 1
    VPASS(0, 1)               // window 2: tiles 2,3
    COMPT(4, pE, gE)          // slot 0
    VPASS(1, 0)               // window 3: tiles 3,4

    // ---- block reduction -> one partial per block ----
#pragma unroll
    for (int off = 32; off > 0; off >>= 1)
        lsum += __shfl_down(lsum, off);
    if (lane == 0) wsum[wv] = lsum;
    __syncthreads();
    if (tid == 0)
        partials[(plane * 8 + by) * 8 + bx] =
            wsum[0] + wsum[1] + wsum[2] + wsum[3];
}

__global__ __launch_bounds__(1024) void ssim_finalize(
        const float* __restrict__ partials, float* __restrict__ out,
        int nparts, double inv_n)
{
    __shared__ double ws[16];
    double s = 0.0;
    for (int i = threadIdx.x; i < nparts; i += 1024)
        s += (double)partials[i];
#pragma unroll
    for (int off = 32; off > 0; off >>= 1)
        s += __shfl_down(s, off);
    if ((threadIdx.x & 63) == 0) ws[threadIdx.x >> 6] = s;
    __syncthreads();
    if (threadIdx.x == 0) {
        double t = 0.0;
#pragma unroll
        for (int i = 0; i < 16; ++i) t += ws[i];
        out[0] = (float)(1.0 - t * inv_n);
    }
}

extern "C" void kernel_launch(void* const* d_in, const int* in_sizes, int n_in,
                              void* d_out, int out_size, void* d_ws, size_t ws_size,
                              hipStream_t stream)
{
    const float* pred = (const float*)d_in[0];
    const float* gt   = (const float*)d_in[1];
    float* out        = (float*)d_out;
    float* partials   = (float*)d_ws;          // 8*8*48 = 3072 floats

    const long n = (long)in_sizes[0];
    const int planes = (int)(n / (long)(IMG * IMG));   // B*C = 48

    dim3 grid(8, 8, planes);                   // 64-col x 64-row strips
    ssim_mfma_ring2<<<grid, 256, 0, stream>>>(pred, gt, partials);
    ssim_finalize<<<1, 1024, 0, stream>>>(partials, out,
                                          8 * 8 * planes, 1.0 / (double)n);
}